// Round 16
// baseline (104.695 us; speedup 1.0000x reference)
//
#include <hip/hip_runtime.h>

#define K_CODES 1024
#define DIM 64
#define OUT_Q 8388608  // 32*64*64*64 quantized elems; loss at [OUT_Q]; indices at [OUT_Q+1..]
#define NPOS 131072
#define MAXC_S 6       // shortlist slots per split (2 splits share a 12-wide row)
#define EPS 4e-3f      // shortlist margin (>=5x worst-case pack+approx skew ~7e-4)
#define BIAS 32.0f     // makes packed distances positive (|2*dot| <= ~26 < 32)

typedef float v2 __attribute__((ext_vector_type(2)));
typedef float f32x4 __attribute__((ext_vector_type(4)));
typedef short bf16x8 __attribute__((ext_vector_type(8)));

#if __has_builtin(__builtin_elementwise_fma)
#define FMA2(a, b, c) __builtin_elementwise_fma((a), (b), (c))
#else
static __device__ inline v2 FMA2(v2 a, v2 b, v2 c) {
    v2 r; r.x = fmaf(a.x, b.x, c.x); r.y = fmaf(a.y, b.y, c.y); return r;
}
#endif

static __device__ inline unsigned short f2bf(float f) {  // RNE f32->bf16
    union { float f; unsigned u; } c; c.f = f;
    unsigned u = c.u;
    u += 0x7fffu + ((u >> 16) & 1u);
    return (unsigned short)(u >> 16);
}
static __device__ inline float bf2f(unsigned short h) {
    union { unsigned u; float f; } c; c.u = ((unsigned)h) << 16;
    return c.f;
}

// ---- pass 1: exact ee[k], biased eeb[k], prepacked B fragments of (-2*e) ----
// Bpack[kt][chunk][lane][j]: chunk 0/1 = hi half0/half1, chunk 2/3 = lo half0/half1.
// B-frag layout for mfma_16x16x32: lane l supplies B[kdim=(l>>4)*8+j][col=l&15].
__global__ void vq_prep(const float* __restrict__ emb, float* __restrict__ ee,
                        float* __restrict__ eeb, unsigned short* __restrict__ Bpack) {
    int k = blockIdx.x * blockDim.x + threadIdx.x;
    if (k < K_CODES) {
        const int kt = k >> 4, col = k & 15;
        float s = 0.f;
        #pragma unroll
        for (int d = 0; d < DIM; ++d) {
            float vv = emb[k * DIM + d];
            s = fmaf(vv, vv, s);
            float m2 = -2.f * vv;            // exact scaling
            unsigned short hh = f2bf(m2);
            unsigned short ll = f2bf(m2 - bf2f(hh));
            const int half = d >> 5;
            const int lane = ((d >> 3) & 3) * 16 + col;
            const int j = d & 7;
            Bpack[kt * 2048 + half * 512 + lane * 8 + j] = hh;
            Bpack[kt * 2048 + (2 + half) * 512 + lane * 8 + j] = ll;
        }
        ee[k] = s;          // exact (recheck path)
        eeb[k] = s + BIAS;  // biased accumulator seed (approx path)
    }
}

// one A-set vs one tile-PAIR: two ee-seeded 6-MFMA chains, merged 3-op/elem best-2.
#define PTILE2(XH0, XL0, XH1, XL1, Eh0, Eh1, El0, El1, Oh0, Oh1, Ol0, Ol1,       \
               SE, SO, IDXE, IDXO, U1, U2)                                       \
    {                                                                            \
        f32x4 aE = {SE, SE, SE, SE};                                             \
        aE = __builtin_amdgcn_mfma_f32_16x16x32_bf16(XH0, Eh0, aE, 0, 0, 0);     \
        aE = __builtin_amdgcn_mfma_f32_16x16x32_bf16(XL0, Eh0, aE, 0, 0, 0);     \
        aE = __builtin_amdgcn_mfma_f32_16x16x32_bf16(XH0, El0, aE, 0, 0, 0);     \
        aE = __builtin_amdgcn_mfma_f32_16x16x32_bf16(XH1, Eh1, aE, 0, 0, 0);     \
        aE = __builtin_amdgcn_mfma_f32_16x16x32_bf16(XL1, Eh1, aE, 0, 0, 0);     \
        aE = __builtin_amdgcn_mfma_f32_16x16x32_bf16(XH1, El1, aE, 0, 0, 0);     \
        f32x4 aO = {SO, SO, SO, SO};                                             \
        aO = __builtin_amdgcn_mfma_f32_16x16x32_bf16(XH0, Oh0, aO, 0, 0, 0);     \
        aO = __builtin_amdgcn_mfma_f32_16x16x32_bf16(XL0, Oh0, aO, 0, 0, 0);     \
        aO = __builtin_amdgcn_mfma_f32_16x16x32_bf16(XH0, Ol0, aO, 0, 0, 0);     \
        aO = __builtin_amdgcn_mfma_f32_16x16x32_bf16(XH1, Oh1, aO, 0, 0, 0);     \
        aO = __builtin_amdgcn_mfma_f32_16x16x32_bf16(XL1, Oh1, aO, 0, 0, 0);     \
        aO = __builtin_amdgcn_mfma_f32_16x16x32_bf16(XH1, Ol1, aO, 0, 0, 0);     \
        _Pragma("unroll")                                                        \
        for (int j = 0; j < 4; ++j) {                                            \
            unsigned uE = (__float_as_uint(aE[j]) & 0xFFFFFFE0u) | (IDXE);       \
            unsigned uO = (__float_as_uint(aO[j]) & 0xFFFFFFE0u) | (IDXO);       \
            unsigned uu = uE < uO ? uE : uO;                /* v_min_u32 */      \
            unsigned mn = uu < U2[j] ? uu : U2[j];          /* v_min_u32 */      \
            U2[j] = U1[j] > mn ? U1[j] : mn;                /* v_max_u32 */      \
            U1[j] = uu < U1[j] ? uu : U1[j];                /* v_min_u32 */      \
        }                                                                        \
    }

// load a tile-pair (split-local even tile TE, odd TE+1) into a named buffer set
#define LOADPAIR(Eh0, Eh1, El0, El1, Oh0, Oh1, Ol0, Ol1, SE, SO, TE)            \
    {                                                                           \
        const unsigned short* pe = bp + (size_t)(TE) * 2048;                    \
        Eh0 = *(const bf16x8*)(pe + 0);                                         \
        Eh1 = *(const bf16x8*)(pe + 512);                                       \
        El0 = *(const bf16x8*)(pe + 1024);                                     \
        El1 = *(const bf16x8*)(pe + 1536);                                      \
        const unsigned short* po = pe + 2048;                                   \
        Oh0 = *(const bf16x8*)(po + 0);                                         \
        Oh1 = *(const bf16x8*)(po + 512);                                       \
        Ol0 = *(const bf16x8*)(po + 1024);                                      \
        Ol1 = *(const bf16x8*)(po + 1536);                                      \
        SE = eeb[(kbase + (TE)) * 16 + li];                                     \
        SO = eeb[(kbase + (TE) + 1) * 16 + li];                                 \
    }

// load one position-tile's A fragments (hi/lo split, 2 K-halves) and pin them
#define LOADA(XH0, XL0, XH1, XL1, POSOFF)                                       \
    {                                                                           \
        _Pragma("unroll")                                                       \
        for (int j = 0; j < 8; ++j) {                                           \
            float v0 = in[ibase + ((size_t)(dbase + j) << 12) + (POSOFF)];      \
            float v1 = in[ibase + ((size_t)(32 + dbase + j) << 12) + (POSOFF)]; \
            unsigned short h0 = f2bf(v0), h1 = f2bf(v1);                        \
            XH0[j] = (short)h0; XL0[j] = (short)f2bf(v0 - bf2f(h0));            \
            XH1[j] = (short)h1; XL1[j] = (short)f2bf(v1 - bf2f(h1));            \
        }                                                                       \
        asm volatile("" : "+v"(XH0), "+v"(XL0), "+v"(XH1), "+v"(XL1));          \
    }

// shortlist emit for one position-tile's merged (U1,U2) candidate sets.
// k = split*512 + (f>>1)*32 + (f&1)*16 + li where f = packed&31 (== split*512 + f*16 + li).
#define EMIT(U1a, U2a, PBASE)                                                                        \
    {                                                                                                \
        _Pragma("unroll")                                                                            \
        for (int j = 0; j < 4; ++j) {                                                                \
            unsigned um = U1a[j];                                                                    \
            _Pragma("unroll")                                                                        \
            for (int m = 1; m < 16; m <<= 1) {                                                       \
                unsigned o = (unsigned)__shfl_xor((int)um, m, 64);                                   \
                um = um < o ? um : o;                                                                \
            }                                                                                        \
            const float thr = __uint_as_float(um & 0xFFFFFFE0u) + EPS;                               \
            bool f1 = __uint_as_float(U1a[j] & 0xFFFFFFE0u) <= thr;                                  \
            bool f2 = __uint_as_float(U2a[j] & 0xFFFFFFE0u) <= thr;                                  \
            unsigned long long b1 = __ballot(f1);                                                    \
            unsigned long long b2 = __ballot(f2);                                                    \
            unsigned fl1 = (unsigned)((b1 >> (g * 16)) & 0xFFFFull);                                 \
            unsigned fl2 = (unsigned)((b2 >> (g * 16)) & 0xFFFFull);                                 \
            const unsigned below = (1u << li) - 1u;                                                  \
            int c1 = __popc(fl1);                                                                    \
            int p1 = __popc(fl1 & below);                                                            \
            int p2 = c1 + __popc(fl2 & below);                                                       \
            const int n_row = (PBASE) + g * 4 + j;                                                   \
            unsigned fA = U1a[j] & 31u, fB = U2a[j] & 31u;                                           \
            if (f1 && p1 < MAXC_S)                                                                   \
                cand[n_row * 12 + sb + p1] = (unsigned short)(ksb + fA * 16u + li);                  \
            if (f2 && p2 < MAXC_S)                                                                   \
                cand[n_row * 12 + sb + p2] = (unsigned short)(ksb + fB * 16u + li);                  \
            if (li == 0) {                                                                           \
                int tot = c1 + __popc(fl2);                                                          \
                cnt[cntb + n_row] = (unsigned short)(tot < MAXC_S ? tot : MAXC_S);                   \
            }                                                                                        \
        }                                                                                            \
    }

// ---- pass 2: MFMA approx distances; 32 pos/wave x 512 codes (K-split x2),
// one-pair-ahead register pipeline (loads issued AFTER the pair's last read) ----
__global__ __launch_bounds__(256, 2) void vq_dist_mfma(
        const float* __restrict__ in, const unsigned short* __restrict__ Bpack,
        const float* __restrict__ eeb,
        unsigned short* __restrict__ cand, unsigned short* __restrict__ cnt) {
    const int t = threadIdx.x;
    const int wv = t >> 6;
    const int l = t & 63;
    const int li = l & 15;
    const int g = l >> 4;
    const int split = blockIdx.x >> 10;       // 0 or 1: code range [split*512, +512)
    const int pblk = blockIdx.x & 1023;
    const int n_base = pblk * 128;            // 128 positions per block (never crosses b)
    const size_t ibase = ((size_t)(n_base >> 12) << 18) + (size_t)(n_base & 4095);
    const int sb = split * MAXC_S;            // slot base within 12-wide cand row
    const unsigned ksb = (unsigned)(split * 512);
    const int cntb = split * NPOS;

    // ---- A fragments: 2 position-tiles x 64 dims, hi/lo split, 2 K-halves ----
    const int dbase = g * 8;
    const int posA = wv * 32 + li;
    bf16x8 XAH0, XAL0, XAH1, XAL1, XBH0, XBL0, XBH1, XBL1;
    LOADA(XAH0, XAL0, XAH1, XAL1, posA);
    LOADA(XBH0, XBL0, XBH1, XBL1, posA + 16);

    unsigned uA1[4], uA2[4], uB1[4], uB2[4];
    #pragma unroll
    for (int j = 0; j < 4; ++j) {
        uA1[j] = uA2[j] = uB1[j] = uB2[j] = 0xFFFFFFFFu;
    }

    // coalesced per-lane stream base within this split's 32-tile range
    const int kbase = split * 32;  // tile units
    const unsigned short* bp = Bpack + (size_t)kbase * 2048 + (size_t)l * 8;

    // two pair-buffers: set P (pairs 0,2,4..) and set Q (pairs 1,3,5..)
    bf16x8 Pe0, Pe1, Pe2, Pe3, Po0, Po1, Po2, Po3;
    bf16x8 Qe0, Qe1, Qe2, Qe3, Qo0, Qo1, Qo2, Qo3;
    float sPe, sPo, sQe, sQo;
    LOADPAIR(Pe0, Pe1, Pe2, Pe3, Po0, Po1, Po2, Po3, sPe, sPo, 0);
    LOADPAIR(Qe0, Qe1, Qe2, Qe3, Qo0, Qo1, Qo2, Qo3, sQe, sQo, 2);

    for (int kt = 0; kt < 32; kt += 4) {
        // compute pair (kt,kt+1) from P, THEN refill P with (kt+4,kt+5):
        // refill overlaps the Q-pair compute below (one full body in flight)
        PTILE2(XAH0, XAL0, XAH1, XAL1, Pe0, Pe1, Pe2, Pe3, Po0, Po1, Po2, Po3,
               sPe, sPo, (unsigned)kt, (unsigned)(kt + 1), uA1, uA2);
        PTILE2(XBH0, XBL0, XBH1, XBL1, Pe0, Pe1, Pe2, Pe3, Po0, Po1, Po2, Po3,
               sPe, sPo, (unsigned)kt, (unsigned)(kt + 1), uB1, uB2);
        LOADPAIR(Pe0, Pe1, Pe2, Pe3, Po0, Po1, Po2, Po3, sPe, sPo, kt + 4);

        // compute pair (kt+2,kt+3) from Q, then refill Q with (kt+6,kt+7)
        PTILE2(XAH0, XAL0, XAH1, XAL1, Qe0, Qe1, Qe2, Qe3, Qo0, Qo1, Qo2, Qo3,
               sQe, sQo, (unsigned)(kt + 2), (unsigned)(kt + 3), uA1, uA2);
        PTILE2(XBH0, XBL0, XBH1, XBL1, Qe0, Qe1, Qe2, Qe3, Qo0, Qo1, Qo2, Qo3,
               sQe, sQo, (unsigned)(kt + 2), (unsigned)(kt + 3), uB1, uB2);
        LOADPAIR(Qe0, Qe1, Qe2, Qe3, Qo0, Qo1, Qo2, Qo3, sQe, sQo, kt + 6);
    }
    // (tail prefetches read tiles up to split-local 35 -> Bpack/eeb padded)

    // ---- shortlist: candidates within EPS of each row's split-local min ----
    EMIT(uA1, uA2, n_base + wv * 32);
    EMIT(uB1, uB2, n_base + wv * 32 + 16);
}

// ---- pass 3: exact f32 recheck of both splits' shortlists + gather + loss ----
__global__ __launch_bounds__(256) void vq_pick(
        const float* __restrict__ in, const float* __restrict__ emb,
        const float* __restrict__ ee, const unsigned short* __restrict__ cand,
        const unsigned short* __restrict__ cnt, float* __restrict__ out,
        float* __restrict__ partials) {
    const int n = blockIdx.x * 256 + threadIdx.x;
    const int w = n & 63;
    const int h = (n >> 6) & 63;
    const int b = n >> 12;
    const size_t base = ((size_t)b << 18) + ((size_t)h << 6) + (size_t)w;

    v2 x[32];
    #pragma unroll
    for (int d = 0; d < 32; ++d) {
        x[d].x = in[base + ((size_t)(2 * d + 0) << 12)];
        x[d].y = in[base + ((size_t)(2 * d + 1) << 12)];
    }
    asm volatile("" : "+v"(x[0]), "+v"(x[1]), "+v"(x[2]), "+v"(x[3]),
                      "+v"(x[4]), "+v"(x[5]), "+v"(x[6]), "+v"(x[7]),
                      "+v"(x[8]), "+v"(x[9]), "+v"(x[10]), "+v"(x[11]),
                      "+v"(x[12]), "+v"(x[13]), "+v"(x[14]), "+v"(x[15]));
    asm volatile("" : "+v"(x[16]), "+v"(x[17]), "+v"(x[18]), "+v"(x[19]),
                      "+v"(x[20]), "+v"(x[21]), "+v"(x[22]), "+v"(x[23]),
                      "+v"(x[24]), "+v"(x[25]), "+v"(x[26]), "+v"(x[27]),
                      "+v"(x[28]), "+v"(x[29]), "+v"(x[30]), "+v"(x[31]));

    // exact f32 distance for each shortlisted code -- bit-identical to R3's scan
    const int c0 = cnt[n];          // split 0: slots 0..5
    const int c1 = cnt[NPOS + n];   // split 1: slots 6..11
    float bestD = 3.4e38f;
    int bestK = 0x7FFFFFFF;
    for (int s = 0; s < c0 + c1; ++s) {
        const int slot = (s < c0) ? s : (MAXC_S + s - c0);
        const int k = (int)cand[n * 12 + slot];
        const v2* __restrict__ e = (const v2*)(emb + (size_t)k * DIM);
        v2 a0 = {0.f, 0.f}, a1 = {0.f, 0.f}, a2 = {0.f, 0.f}, a3 = {0.f, 0.f};
        #pragma unroll
        for (int d = 0; d < 32; d += 4) {
            a0 = FMA2(x[d + 0], e[d + 0], a0);
            a1 = FMA2(x[d + 1], e[d + 1], a1);
            a2 = FMA2(x[d + 2], e[d + 2], a2);
            a3 = FMA2(x[d + 3], e[d + 3], a3);
        }
        v2 s2 = (a0 + a1) + (a2 + a3);
        float dk = fmaf(-2.f, s2.x + s2.y, ee[k]);
        // lexicographic (dist, k) min == ascending-k strict-< first occurrence
        if (dk < bestD || (dk == bestD && k < bestK)) { bestD = dk; bestK = k; }
    }
    out[OUT_Q + 1 + n] = (float)bestK;

    const v2* __restrict__ eq = (const v2*)(emb + (size_t)bestK * DIM);
    v2 errs2 = {0.f, 0.f};
    #pragma unroll
    for (int d = 0; d < 32; ++d) {
        v2 q = eq[d];
        v2 diff = q - x[d];
        errs2 = FMA2(diff, diff, errs2);
        out[base + ((size_t)(2 * d + 0) << 12)] = q.x;
        out[base + ((size_t)(2 * d + 1) << 12)] = q.y;
    }
    float errs = errs2.x + errs2.y;

    #pragma unroll
    for (int off = 32; off > 0; off >>= 1) errs += __shfl_xor(errs, off, 64);

    __shared__ float red[4];
    const int wave = threadIdx.x >> 6;
    const int lane = threadIdx.x & 63;
    if (lane == 0) red[wave] = errs;
    __syncthreads();
    if (threadIdx.x == 0) {
        partials[blockIdx.x] = (red[0] + red[1]) + (red[2] + red[3]);
    }
}

// ---- pass 4: parallel deterministic loss reduction (fixed tree order) ----
__global__ __launch_bounds__(256) void vq_loss(const float* __restrict__ partials,
                                               float* __restrict__ out) {
    const int t = threadIdx.x;
    float s = partials[t] + partials[t + 256];
    #pragma unroll
    for (int off = 32; off > 0; off >>= 1) s += __shfl_xor(s, off, 64);
    __shared__ float red[4];
    const int wave = t >> 6;
    const int lane = t & 63;
    if (lane == 0) red[wave] = s;
    __syncthreads();
    if (t == 0) {
        out[OUT_Q] = ((red[0] + red[1]) + (red[2] + red[3])) * (float)(1.25 / 8388608.0);
    }
}

extern "C" void kernel_launch(void* const* d_in, const int* in_sizes, int n_in,
                              void* d_out, int out_size, void* d_ws, size_t ws_size,
                              hipStream_t stream) {
    const float* in  = (const float*)d_in[0];   // [32,64,64,64] f32
    const float* emb = (const float*)d_in[1];   // [1024,64] f32
    float* out = (float*)d_out;

    // ws layout: ee f32[1024] | eeb f32[1024+64 pad] | Bpack u16[68*2048 pad] |
    //            cand u16[NPOS*12] | cnt u16[2*NPOS] | partials f32[512]   (~3.93 MB)
    char* w = (char*)d_ws;
    float* ee = (float*)w;                      w += K_CODES * 4;
    float* eeb = (float*)w;                     w += (K_CODES + 64) * 4;
    unsigned short* Bpack = (unsigned short*)w; w += (size_t)68 * 2048 * 2;
    unsigned short* cand = (unsigned short*)w;  w += (size_t)NPOS * 12 * 2;
    unsigned short* cnt = (unsigned short*)w;   w += (size_t)2 * NPOS * 2;
    float* partials = (float*)w;

    vq_prep<<<4, 256, 0, stream>>>(emb, ee, eeb, Bpack);
    vq_dist_mfma<<<2048, 256, 0, stream>>>(in, Bpack, eeb, cand, cnt);
    vq_pick<<<512, 256, 0, stream>>>(in, emb, ee, cand, cnt, out, partials);
    vq_loss<<<1, 256, 0, stream>>>(partials, out);
}

// Round 17
// 86.013 us; speedup vs baseline: 1.2172x; 1.2172x over previous
//
#include <hip/hip_runtime.h>

#define K_CODES 1024
#define DIM 64
#define OUT_Q 8388608  // 32*64*64*64 quantized elems; loss at [OUT_Q]; indices at [OUT_Q+1..]
#define NPOS 131072
#define MAXC_S 6       // shortlist slots per split (2 splits share a 12-wide row)
#define EPS 4e-3f      // shortlist margin (>=5x worst-case pack+approx skew ~7e-4)
#define BIAS 32.0f     // makes packed distances positive (|2*dot| <= ~26 < 32)

typedef float v2 __attribute__((ext_vector_type(2)));
typedef float f32x4 __attribute__((ext_vector_type(4)));
typedef short bf16x8 __attribute__((ext_vector_type(8)));

#if __has_builtin(__builtin_elementwise_fma)
#define FMA2(a, b, c) __builtin_elementwise_fma((a), (b), (c))
#else
static __device__ inline v2 FMA2(v2 a, v2 b, v2 c) {
    v2 r; r.x = fmaf(a.x, b.x, c.x); r.y = fmaf(a.y, b.y, c.y); return r;
}
#endif

static __device__ inline unsigned short f2bf(float f) {  // RNE f32->bf16
    union { float f; unsigned u; } c; c.f = f;
    unsigned u = c.u;
    u += 0x7fffu + ((u >> 16) & 1u);
    return (unsigned short)(u >> 16);
}
static __device__ inline float bf2f(unsigned short h) {
    union { unsigned u; float f; } c; c.u = ((unsigned)h) << 16;
    return c.f;
}

// ---- pass 1: ee[k], biased eeb[k], prepacked B fragments of (-2*e) ----
// PARALLEL: one wave per code k (lane = dim d); 256 blocks x 4 waves = 1024 codes.
// emb reads fully coalesced (256B/wave); ee via deterministic shfl tree.
// Bpack[kt][chunk][lane][j]: chunk 0/1 = hi half0/half1, chunk 2/3 = lo half0/half1.
__global__ __launch_bounds__(256) void vq_prep(
        const float* __restrict__ emb, float* __restrict__ ee,
        float* __restrict__ eeb, unsigned short* __restrict__ Bpack) {
    const int t = threadIdx.x;
    const int wv = t >> 6;
    const int d = t & 63;
    const int k = blockIdx.x * 4 + wv;
    const int kt = k >> 4, col = k & 15;

    const float vv = emb[k * DIM + d];
    float s = vv * vv;
    #pragma unroll
    for (int off = 32; off > 0; off >>= 1) s += __shfl_xor(s, off, 64);
    if (d == 0) {
        ee[k] = s;          // exact-path norm (recheck)
        eeb[k] = s + BIAS;  // biased accumulator seed (approx path)
    }

    const float m2 = -2.f * vv;  // exact scaling
    const unsigned short hh = f2bf(m2);
    const unsigned short ll = f2bf(m2 - bf2f(hh));
    const int half = d >> 5;
    const int lane = ((d >> 3) & 3) * 16 + col;
    const int j = d & 7;
    Bpack[kt * 2048 + half * 512 + lane * 8 + j] = hh;
    Bpack[kt * 2048 + (2 + half) * 512 + lane * 8 + j] = ll;
}

// one A-set vs one tile-PAIR: two ee-seeded 6-MFMA chains, merged 3-op/elem best-2.
#define PTILE2(XH0, XL0, XH1, XL1, Eh0, Eh1, El0, El1, Oh0, Oh1, Ol0, Ol1,       \
               SE, SO, IDXE, IDXO, U1, U2)                                       \
    {                                                                            \
        f32x4 aE = {SE, SE, SE, SE};                                             \
        aE = __builtin_amdgcn_mfma_f32_16x16x32_bf16(XH0, Eh0, aE, 0, 0, 0);     \
        aE = __builtin_amdgcn_mfma_f32_16x16x32_bf16(XL0, Eh0, aE, 0, 0, 0);     \
        aE = __builtin_amdgcn_mfma_f32_16x16x32_bf16(XH0, El0, aE, 0, 0, 0);     \
        aE = __builtin_amdgcn_mfma_f32_16x16x32_bf16(XH1, Eh1, aE, 0, 0, 0);     \
        aE = __builtin_amdgcn_mfma_f32_16x16x32_bf16(XL1, Eh1, aE, 0, 0, 0);     \
        aE = __builtin_amdgcn_mfma_f32_16x16x32_bf16(XH1, El1, aE, 0, 0, 0);     \
        f32x4 aO = {SO, SO, SO, SO};                                             \
        aO = __builtin_amdgcn_mfma_f32_16x16x32_bf16(XH0, Oh0, aO, 0, 0, 0);     \
        aO = __builtin_amdgcn_mfma_f32_16x16x32_bf16(XL0, Oh0, aO, 0, 0, 0);     \
        aO = __builtin_amdgcn_mfma_f32_16x16x32_bf16(XH0, Ol0, aO, 0, 0, 0);     \
        aO = __builtin_amdgcn_mfma_f32_16x16x32_bf16(XH1, Oh1, aO, 0, 0, 0);     \
        aO = __builtin_amdgcn_mfma_f32_16x16x32_bf16(XL1, Oh1, aO, 0, 0, 0);     \
        aO = __builtin_amdgcn_mfma_f32_16x16x32_bf16(XH1, Ol1, aO, 0, 0, 0);     \
        _Pragma("unroll")                                                        \
        for (int j = 0; j < 4; ++j) {                                            \
            unsigned uE = (__float_as_uint(aE[j]) & 0xFFFFFFE0u) | (IDXE);       \
            unsigned uO = (__float_as_uint(aO[j]) & 0xFFFFFFE0u) | (IDXO);       \
            unsigned uu = uE < uO ? uE : uO;                /* v_min_u32 */      \
            unsigned mn = uu < U2[j] ? uu : U2[j];          /* v_min_u32 */      \
            U2[j] = U1[j] > mn ? U1[j] : mn;                /* v_max_u32 */      \
            U1[j] = uu < U1[j] ? uu : U1[j];                /* v_min_u32 */      \
        }                                                                        \
    }

// load one position-tile's A fragments (hi/lo split, 2 K-halves) and pin them
#define LOADA(XH0, XL0, XH1, XL1, POSOFF)                                       \
    {                                                                           \
        _Pragma("unroll")                                                       \
        for (int j = 0; j < 8; ++j) {                                           \
            float v0 = in[ibase + ((size_t)(dbase + j) << 12) + (POSOFF)];      \
            float v1 = in[ibase + ((size_t)(32 + dbase + j) << 12) + (POSOFF)]; \
            unsigned short h0 = f2bf(v0), h1 = f2bf(v1);                        \
            XH0[j] = (short)h0; XL0[j] = (short)f2bf(v0 - bf2f(h0));            \
            XH1[j] = (short)h1; XL1[j] = (short)f2bf(v1 - bf2f(h1));            \
        }                                                                       \
        asm volatile("" : "+v"(XH0), "+v"(XL0), "+v"(XH1), "+v"(XL1));          \
    }

// shortlist emit for one position-tile's merged (U1,U2) candidate sets.
// k = split*512 + f*16 + li where f = packed&31.
#define EMIT(U1a, U2a, PBASE)                                                                        \
    {                                                                                                \
        _Pragma("unroll")                                                                            \
        for (int j = 0; j < 4; ++j) {                                                                \
            unsigned um = U1a[j];                                                                    \
            _Pragma("unroll")                                                                        \
            for (int m = 1; m < 16; m <<= 1) {                                                       \
                unsigned o = (unsigned)__shfl_xor((int)um, m, 64);                                   \
                um = um < o ? um : o;                                                                \
            }                                                                                        \
            const float thr = __uint_as_float(um & 0xFFFFFFE0u) + EPS;                               \
            bool f1 = __uint_as_float(U1a[j] & 0xFFFFFFE0u) <= thr;                                  \
            bool f2 = __uint_as_float(U2a[j] & 0xFFFFFFE0u) <= thr;                                  \
            unsigned long long b1 = __ballot(f1);                                                    \
            unsigned long long b2 = __ballot(f2);                                                    \
            unsigned fl1 = (unsigned)((b1 >> (g * 16)) & 0xFFFFull);                                 \
            unsigned fl2 = (unsigned)((b2 >> (g * 16)) & 0xFFFFull);                                 \
            const unsigned below = (1u << li) - 1u;                                                  \
            int c1 = __popc(fl1);                                                                    \
            int p1 = __popc(fl1 & below);                                                            \
            int p2 = c1 + __popc(fl2 & below);                                                       \
            const int n_row = (PBASE) + g * 4 + j;                                                   \
            unsigned fA = U1a[j] & 31u, fB = U2a[j] & 31u;                                           \
            if (f1 && p1 < MAXC_S)                                                                   \
                cand[n_row * 12 + sb + p1] = (unsigned short)(ksb + fA * 16u + li);                  \
            if (f2 && p2 < MAXC_S)                                                                   \
                cand[n_row * 12 + sb + p2] = (unsigned short)(ksb + fB * 16u + li);                  \
            if (li == 0) {                                                                           \
                int tot = c1 + __popc(fl2);                                                          \
                cnt[cntb + n_row] = (unsigned short)(tot < MAXC_S ? tot : MAXC_S);                   \
            }                                                                                        \
        }                                                                                            \
    }

// ---- pass 2: MFMA approx distances; 32 pos/wave x 512 codes (K-split x2) ----
// R15 structure verbatim (proven 59us / 48 VGPR / 41% occ); R16's 2-pair
// register pipeline regressed (compiler sank the loads; VGPR 52 proves it).
__global__ __launch_bounds__(256, 4) void vq_dist_mfma(
        const float* __restrict__ in, const unsigned short* __restrict__ Bpack,
        const float* __restrict__ eeb,
        unsigned short* __restrict__ cand, unsigned short* __restrict__ cnt) {
    const int t = threadIdx.x;
    const int wv = t >> 6;
    const int l = t & 63;
    const int li = l & 15;
    const int g = l >> 4;
    const int split = blockIdx.x >> 10;       // 0 or 1: code range [split*512, +512)
    const int pblk = blockIdx.x & 1023;
    const int n_base = pblk * 128;            // 128 positions per block (never crosses b)
    const size_t ibase = ((size_t)(n_base >> 12) << 18) + (size_t)(n_base & 4095);
    const int sb = split * MAXC_S;            // slot base within 12-wide cand row
    const unsigned ksb = (unsigned)(split * 512);
    const int cntb = split * NPOS;

    // ---- A fragments: 2 position-tiles x 64 dims, hi/lo split, 2 K-halves ----
    const int dbase = g * 8;
    const int posA = wv * 32 + li;
    bf16x8 XAH0, XAL0, XAH1, XAL1, XBH0, XBL0, XBH1, XBL1;
    LOADA(XAH0, XAL0, XAH1, XAL1, posA);
    LOADA(XBH0, XBL0, XBH1, XBL1, posA + 16);

    unsigned uA1[4], uA2[4], uB1[4], uB2[4];
    #pragma unroll
    for (int j = 0; j < 4; ++j) {
        uA1[j] = uA2[j] = uB1[j] = uB2[j] = 0xFFFFFFFFu;
    }

    // coalesced per-lane stream base within this split's 32-tile range
    const int kbase = split * 32;  // tile units
    const unsigned short* bp = Bpack + (size_t)kbase * 2048 + (size_t)l * 8;

    // preload first tile-pair's even tile into reg set A
    bf16x8 h0A = *(const bf16x8*)(bp + 0);
    bf16x8 h1A = *(const bf16x8*)(bp + 512);
    bf16x8 l0A = *(const bf16x8*)(bp + 1024);
    bf16x8 l1A = *(const bf16x8*)(bp + 1536);
    float eA = eeb[kbase * 16 + li];

    for (int kt = 0; kt < 32; kt += 2) {
        const unsigned idxE = (unsigned)(kt);          // (pair<<1)   = kt
        const unsigned idxO = (unsigned)(kt + 1);      // (pair<<1)|1 = kt+1
        // load odd tile into reg set B
        const unsigned short* p1 = bp + (size_t)(kt + 1) * 2048;
        bf16x8 h0B = *(const bf16x8*)(p1 + 0);
        bf16x8 h1B = *(const bf16x8*)(p1 + 512);
        bf16x8 l0B = *(const bf16x8*)(p1 + 1024);
        bf16x8 l1B = *(const bf16x8*)(p1 + 1536);
        float eB = eeb[(kbase + kt + 1) * 16 + li];

        PTILE2(XAH0, XAL0, XAH1, XAL1, h0A, h1A, l0A, l1A, h0B, h1B, l0B, l1B,
               eA, eB, idxE, idxO, uA1, uA2);
        PTILE2(XBH0, XBL0, XBH1, XBL1, h0A, h1A, l0A, l1A, h0B, h1B, l0B, l1B,
               eA, eB, idxE, idxO, uB1, uB2);

        // prefetch next even tile into reg set A (Bpack/eeb padded: safe at end)
        const unsigned short* p2 = bp + (size_t)(kt + 2) * 2048;
        h0A = *(const bf16x8*)(p2 + 0);
        h1A = *(const bf16x8*)(p2 + 512);
        l0A = *(const bf16x8*)(p2 + 1024);
        l1A = *(const bf16x8*)(p2 + 1536);
        eA = eeb[(kbase + kt + 2) * 16 + li];
    }

    // ---- shortlist: candidates within EPS of each row's split-local min ----
    EMIT(uA1, uA2, n_base + wv * 32);
    EMIT(uB1, uB2, n_base + wv * 32 + 16);
}

// ---- pass 3: exact f32 recheck of both splits' shortlists + gather + loss ----
__global__ __launch_bounds__(256) void vq_pick(
        const float* __restrict__ in, const float* __restrict__ emb,
        const float* __restrict__ ee, const unsigned short* __restrict__ cand,
        const unsigned short* __restrict__ cnt, float* __restrict__ out,
        float* __restrict__ partials) {
    const int n = blockIdx.x * 256 + threadIdx.x;
    const int w = n & 63;
    const int h = (n >> 6) & 63;
    const int b = n >> 12;
    const size_t base = ((size_t)b << 18) + ((size_t)h << 6) + (size_t)w;

    v2 x[32];
    #pragma unroll
    for (int d = 0; d < 32; ++d) {
        x[d].x = in[base + ((size_t)(2 * d + 0) << 12)];
        x[d].y = in[base + ((size_t)(2 * d + 1) << 12)];
    }
    asm volatile("" : "+v"(x[0]), "+v"(x[1]), "+v"(x[2]), "+v"(x[3]),
                      "+v"(x[4]), "+v"(x[5]), "+v"(x[6]), "+v"(x[7]),
                      "+v"(x[8]), "+v"(x[9]), "+v"(x[10]), "+v"(x[11]),
                      "+v"(x[12]), "+v"(x[13]), "+v"(x[14]), "+v"(x[15]));
    asm volatile("" : "+v"(x[16]), "+v"(x[17]), "+v"(x[18]), "+v"(x[19]),
                      "+v"(x[20]), "+v"(x[21]), "+v"(x[22]), "+v"(x[23]),
                      "+v"(x[24]), "+v"(x[25]), "+v"(x[26]), "+v"(x[27]),
                      "+v"(x[28]), "+v"(x[29]), "+v"(x[30]), "+v"(x[31]));

    // exact f32 distance for each shortlisted code
    const int c0 = cnt[n];          // split 0: slots 0..5
    const int c1 = cnt[NPOS + n];   // split 1: slots 6..11
    float bestD = 3.4e38f;
    int bestK = 0x7FFFFFFF;
    for (int s = 0; s < c0 + c1; ++s) {
        const int slot = (s < c0) ? s : (MAXC_S + s - c0);
        const int k = (int)cand[n * 12 + slot];
        const v2* __restrict__ e = (const v2*)(emb + (size_t)k * DIM);
        v2 a0 = {0.f, 0.f}, a1 = {0.f, 0.f}, a2 = {0.f, 0.f}, a3 = {0.f, 0.f};
        #pragma unroll
        for (int d = 0; d < 32; d += 4) {
            a0 = FMA2(x[d + 0], e[d + 0], a0);
            a1 = FMA2(x[d + 1], e[d + 1], a1);
            a2 = FMA2(x[d + 2], e[d + 2], a2);
            a3 = FMA2(x[d + 3], e[d + 3], a3);
        }
        v2 s2 = (a0 + a1) + (a2 + a3);
        float dk = fmaf(-2.f, s2.x + s2.y, ee[k]);
        // lexicographic (dist, k) min == ascending-k strict-< first occurrence
        if (dk < bestD || (dk == bestD && k < bestK)) { bestD = dk; bestK = k; }
    }
    out[OUT_Q + 1 + n] = (float)bestK;

    const v2* __restrict__ eq = (const v2*)(emb + (size_t)bestK * DIM);
    v2 errs2 = {0.f, 0.f};
    #pragma unroll
    for (int d = 0; d < 32; ++d) {
        v2 q = eq[d];
        v2 diff = q - x[d];
        errs2 = FMA2(diff, diff, errs2);
        out[base + ((size_t)(2 * d + 0) << 12)] = q.x;
        out[base + ((size_t)(2 * d + 1) << 12)] = q.y;
    }
    float errs = errs2.x + errs2.y;

    #pragma unroll
    for (int off = 32; off > 0; off >>= 1) errs += __shfl_xor(errs, off, 64);

    __shared__ float red[4];
    const int wave = threadIdx.x >> 6;
    const int lane = threadIdx.x & 63;
    if (lane == 0) red[wave] = errs;
    __syncthreads();
    if (threadIdx.x == 0) {
        partials[blockIdx.x] = (red[0] + red[1]) + (red[2] + red[3]);
    }
}

// ---- pass 4: parallel deterministic loss reduction (fixed tree order) ----
__global__ __launch_bounds__(256) void vq_loss(const float* __restrict__ partials,
                                               float* __restrict__ out) {
    const int t = threadIdx.x;
    float s = partials[t] + partials[t + 256];
    #pragma unroll
    for (int off = 32; off > 0; off >>= 1) s += __shfl_xor(s, off, 64);
    __shared__ float red[4];
    const int wave = t >> 6;
    const int lane = t & 63;
    if (lane == 0) red[wave] = s;
    __syncthreads();
    if (t == 0) {
        out[OUT_Q] = ((red[0] + red[1]) + (red[2] + red[3])) * (float)(1.25 / 8388608.0);
    }
}

extern "C" void kernel_launch(void* const* d_in, const int* in_sizes, int n_in,
                              void* d_out, int out_size, void* d_ws, size_t ws_size,
                              hipStream_t stream) {
    const float* in  = (const float*)d_in[0];   // [32,64,64,64] f32
    const float* emb = (const float*)d_in[1];   // [1024,64] f32
    float* out = (float*)d_out;

    // ws layout: ee f32[1024] | eeb f32[1024+64 pad] | Bpack u16[68*2048 pad] |
    //            cand u16[NPOS*12] | cnt u16[2*NPOS] | partials f32[512]   (~3.93 MB)
    char* w = (char*)d_ws;
    float* ee = (float*)w;                      w += K_CODES * 4;
    float* eeb = (float*)w;                     w += (K_CODES + 64) * 4;
    unsigned short* Bpack = (unsigned short*)w; w += (size_t)68 * 2048 * 2;
    unsigned short* cand = (unsigned short*)w;  w += (size_t)NPOS * 12 * 2;
    unsigned short* cnt = (unsigned short*)w;   w += (size_t)2 * NPOS * 2;
    float* partials = (float*)w;

    vq_prep<<<256, 256, 0, stream>>>(emb, ee, eeb, Bpack);
    vq_dist_mfma<<<2048, 256, 0, stream>>>(in, Bpack, eeb, cand, cnt);
    vq_pick<<<512, 256, 0, stream>>>(in, emb, ee, cand, cnt, out, partials);
    vq_loss<<<1, 256, 0, stream>>>(partials, out);
}

// Round 18
// 82.024 us; speedup vs baseline: 1.2764x; 1.0486x over previous
//
#include <hip/hip_runtime.h>

#define K_CODES 1024
#define DIM 64
#define OUT_Q 8388608  // 32*64*64*64 quantized elems; loss at [OUT_Q]; indices at [OUT_Q+1..]
#define NPOS 131072
#define MAXC_S 6       // shortlist slots per split (2 splits share a 12-wide row)
#define EPS 4e-3f      // shortlist margin (>=5x worst-case pack+approx skew ~7e-4)
#define BIAS 32.0f     // makes packed distances positive (|2*dot| <= ~26 < 32)

typedef float v2 __attribute__((ext_vector_type(2)));
typedef float f32x4 __attribute__((ext_vector_type(4)));
typedef short bf16x8 __attribute__((ext_vector_type(8)));

#if __has_builtin(__builtin_elementwise_fma)
#define FMA2(a, b, c) __builtin_elementwise_fma((a), (b), (c))
#else
static __device__ inline v2 FMA2(v2 a, v2 b, v2 c) {
    v2 r; r.x = fmaf(a.x, b.x, c.x); r.y = fmaf(a.y, b.y, c.y); return r;
}
#endif

static __device__ inline unsigned short f2bf(float f) {  // RNE f32->bf16
    union { float f; unsigned u; } c; c.f = f;
    unsigned u = c.u;
    u += 0x7fffu + ((u >> 16) & 1u);
    return (unsigned short)(u >> 16);
}
static __device__ inline float bf2f(unsigned short h) {
    union { unsigned u; float f; } c; c.u = ((unsigned)h) << 16;
    return c.f;
}

// ---- pass 1: ee[k], biased eeb[k], prepacked B fragments of (-2*e) ----
// PARALLEL: one wave per code k (lane = dim d); 256 blocks x 4 waves = 1024 codes.
__global__ __launch_bounds__(256) void vq_prep(
        const float* __restrict__ emb, float* __restrict__ ee,
        float* __restrict__ eeb, unsigned short* __restrict__ Bpack) {
    const int t = threadIdx.x;
    const int wv = t >> 6;
    const int d = t & 63;
    const int k = blockIdx.x * 4 + wv;
    const int kt = k >> 4, col = k & 15;

    const float vv = emb[k * DIM + d];
    float s = vv * vv;
    #pragma unroll
    for (int off = 32; off > 0; off >>= 1) s += __shfl_xor(s, off, 64);
    if (d == 0) {
        ee[k] = s;          // exact-path norm (recheck)
        eeb[k] = s + BIAS;  // biased accumulator seed (approx path)
    }

    const float m2 = -2.f * vv;  // exact scaling
    const unsigned short hh = f2bf(m2);
    const unsigned short ll = f2bf(m2 - bf2f(hh));
    const int half = d >> 5;
    const int lane = ((d >> 3) & 3) * 16 + col;
    const int j = d & 7;
    Bpack[kt * 2048 + half * 512 + lane * 8 + j] = hh;
    Bpack[kt * 2048 + (2 + half) * 512 + lane * 8 + j] = ll;
}

// one A-set vs one tile-PAIR: two ee-seeded 6-MFMA chains, merged 3-op/elem best-2.
#define PTILE2(XH0, XL0, XH1, XL1, Eh0, Eh1, El0, El1, Oh0, Oh1, Ol0, Ol1,       \
               SE, SO, IDXE, IDXO, U1, U2)                                       \
    {                                                                            \
        f32x4 aE = {SE, SE, SE, SE};                                             \
        aE = __builtin_amdgcn_mfma_f32_16x16x32_bf16(XH0, Eh0, aE, 0, 0, 0);     \
        aE = __builtin_amdgcn_mfma_f32_16x16x32_bf16(XL0, Eh0, aE, 0, 0, 0);     \
        aE = __builtin_amdgcn_mfma_f32_16x16x32_bf16(XH0, El0, aE, 0, 0, 0);     \
        aE = __builtin_amdgcn_mfma_f32_16x16x32_bf16(XH1, Eh1, aE, 0, 0, 0);     \
        aE = __builtin_amdgcn_mfma_f32_16x16x32_bf16(XL1, Eh1, aE, 0, 0, 0);     \
        aE = __builtin_amdgcn_mfma_f32_16x16x32_bf16(XH1, El1, aE, 0, 0, 0);     \
        f32x4 aO = {SO, SO, SO, SO};                                             \
        aO = __builtin_amdgcn_mfma_f32_16x16x32_bf16(XH0, Oh0, aO, 0, 0, 0);     \
        aO = __builtin_amdgcn_mfma_f32_16x16x32_bf16(XL0, Oh0, aO, 0, 0, 0);     \
        aO = __builtin_amdgcn_mfma_f32_16x16x32_bf16(XH0, Ol0, aO, 0, 0, 0);     \
        aO = __builtin_amdgcn_mfma_f32_16x16x32_bf16(XH1, Oh1, aO, 0, 0, 0);     \
        aO = __builtin_amdgcn_mfma_f32_16x16x32_bf16(XL1, Oh1, aO, 0, 0, 0);     \
        aO = __builtin_amdgcn_mfma_f32_16x16x32_bf16(XH1, Ol1, aO, 0, 0, 0);     \
        _Pragma("unroll")                                                        \
        for (int j = 0; j < 4; ++j) {                                            \
            unsigned uE = (__float_as_uint(aE[j]) & 0xFFFFFFE0u) | (IDXE);       \
            unsigned uO = (__float_as_uint(aO[j]) & 0xFFFFFFE0u) | (IDXO);       \
            unsigned uu = uE < uO ? uE : uO;                /* v_min_u32 */      \
            unsigned mn = uu < U2[j] ? uu : U2[j];          /* v_min_u32 */      \
            U2[j] = U1[j] > mn ? U1[j] : mn;                /* v_max_u32 */      \
            U1[j] = uu < U1[j] ? uu : U1[j];                /* v_min_u32 */      \
        }                                                                        \
    }

// load one position-tile's A fragments (hi/lo split, 2 K-halves) and pin them
#define LOADA(XH0, XL0, XH1, XL1, POSOFF)                                       \
    {                                                                           \
        _Pragma("unroll")                                                       \
        for (int j = 0; j < 8; ++j) {                                           \
            float v0 = in[ibase + ((size_t)(dbase + j) << 12) + (POSOFF)];      \
            float v1 = in[ibase + ((size_t)(32 + dbase + j) << 12) + (POSOFF)]; \
            unsigned short h0 = f2bf(v0), h1 = f2bf(v1);                        \
            XH0[j] = (short)h0; XL0[j] = (short)f2bf(v0 - bf2f(h0));            \
            XH1[j] = (short)h1; XL1[j] = (short)f2bf(v1 - bf2f(h1));            \
        }                                                                       \
        asm volatile("" : "+v"(XH0), "+v"(XL0), "+v"(XH1), "+v"(XL1));          \
    }

// shortlist emit for one position-tile's merged (U1,U2) candidate sets.
// k = split*512 + f*16 + li where f = packed&31.
#define EMIT(U1a, U2a, PBASE)                                                                        \
    {                                                                                                \
        _Pragma("unroll")                                                                            \
        for (int j = 0; j < 4; ++j) {                                                                \
            unsigned um = U1a[j];                                                                    \
            _Pragma("unroll")                                                                        \
            for (int m = 1; m < 16; m <<= 1) {                                                       \
                unsigned o = (unsigned)__shfl_xor((int)um, m, 64);                                   \
                um = um < o ? um : o;                                                                \
            }                                                                                        \
            const float thr = __uint_as_float(um & 0xFFFFFFE0u) + EPS;                               \
            bool f1 = __uint_as_float(U1a[j] & 0xFFFFFFE0u) <= thr;                                  \
            bool f2 = __uint_as_float(U2a[j] & 0xFFFFFFE0u) <= thr;                                  \
            unsigned long long b1 = __ballot(f1);                                                    \
            unsigned long long b2 = __ballot(f2);                                                    \
            unsigned fl1 = (unsigned)((b1 >> (g * 16)) & 0xFFFFull);                                 \
            unsigned fl2 = (unsigned)((b2 >> (g * 16)) & 0xFFFFull);                                 \
            const unsigned below = (1u << li) - 1u;                                                  \
            int c1 = __popc(fl1);                                                                    \
            int p1 = __popc(fl1 & below);                                                            \
            int p2 = c1 + __popc(fl2 & below);                                                       \
            const int n_row = (PBASE) + g * 4 + j;                                                   \
            unsigned fA = U1a[j] & 31u, fB = U2a[j] & 31u;                                           \
            if (f1 && p1 < MAXC_S)                                                                   \
                cand[n_row * 12 + sb + p1] = (unsigned short)(ksb + fA * 16u + li);                  \
            if (f2 && p2 < MAXC_S)                                                                   \
                cand[n_row * 12 + sb + p2] = (unsigned short)(ksb + fB * 16u + li);                  \
            if (li == 0) {                                                                           \
                int tot = c1 + __popc(fl2);                                                          \
                cnt[cntb + n_row] = (unsigned short)(tot < MAXC_S ? tot : MAXC_S);                   \
            }                                                                                        \
        }                                                                                            \
    }

// ---- pass 2: MFMA approx distances; 32 pos/wave x 512 codes (K-split x2) ----
// R15 structure verbatim (proven 59us / 48 VGPR / 41% occ).
__global__ __launch_bounds__(256, 4) void vq_dist_mfma(
        const float* __restrict__ in, const unsigned short* __restrict__ Bpack,
        const float* __restrict__ eeb,
        unsigned short* __restrict__ cand, unsigned short* __restrict__ cnt) {
    const int t = threadIdx.x;
    const int wv = t >> 6;
    const int l = t & 63;
    const int li = l & 15;
    const int g = l >> 4;
    const int split = blockIdx.x >> 10;       // 0 or 1: code range [split*512, +512)
    const int pblk = blockIdx.x & 1023;
    const int n_base = pblk * 128;            // 128 positions per block (never crosses b)
    const size_t ibase = ((size_t)(n_base >> 12) << 18) + (size_t)(n_base & 4095);
    const int sb = split * MAXC_S;            // slot base within 12-wide cand row
    const unsigned ksb = (unsigned)(split * 512);
    const int cntb = split * NPOS;

    // ---- A fragments: 2 position-tiles x 64 dims, hi/lo split, 2 K-halves ----
    const int dbase = g * 8;
    const int posA = wv * 32 + li;
    bf16x8 XAH0, XAL0, XAH1, XAL1, XBH0, XBL0, XBH1, XBL1;
    LOADA(XAH0, XAL0, XAH1, XAL1, posA);
    LOADA(XBH0, XBL0, XBH1, XBL1, posA + 16);

    unsigned uA1[4], uA2[4], uB1[4], uB2[4];
    #pragma unroll
    for (int j = 0; j < 4; ++j) {
        uA1[j] = uA2[j] = uB1[j] = uB2[j] = 0xFFFFFFFFu;
    }

    // coalesced per-lane stream base within this split's 32-tile range
    const int kbase = split * 32;  // tile units
    const unsigned short* bp = Bpack + (size_t)kbase * 2048 + (size_t)l * 8;

    // preload first tile-pair's even tile into reg set A
    bf16x8 h0A = *(const bf16x8*)(bp + 0);
    bf16x8 h1A = *(const bf16x8*)(bp + 512);
    bf16x8 l0A = *(const bf16x8*)(bp + 1024);
    bf16x8 l1A = *(const bf16x8*)(bp + 1536);
    float eA = eeb[kbase * 16 + li];

    for (int kt = 0; kt < 32; kt += 2) {
        const unsigned idxE = (unsigned)(kt);
        const unsigned idxO = (unsigned)(kt + 1);
        // load odd tile into reg set B
        const unsigned short* p1 = bp + (size_t)(kt + 1) * 2048;
        bf16x8 h0B = *(const bf16x8*)(p1 + 0);
        bf16x8 h1B = *(const bf16x8*)(p1 + 512);
        bf16x8 l0B = *(const bf16x8*)(p1 + 1024);
        bf16x8 l1B = *(const bf16x8*)(p1 + 1536);
        float eB = eeb[(kbase + kt + 1) * 16 + li];

        PTILE2(XAH0, XAL0, XAH1, XAL1, h0A, h1A, l0A, l1A, h0B, h1B, l0B, l1B,
               eA, eB, idxE, idxO, uA1, uA2);
        PTILE2(XBH0, XBL0, XBH1, XBL1, h0A, h1A, l0A, l1A, h0B, h1B, l0B, l1B,
               eA, eB, idxE, idxO, uB1, uB2);

        // prefetch next even tile into reg set A (Bpack/eeb padded: safe at end)
        const unsigned short* p2 = bp + (size_t)(kt + 2) * 2048;
        h0A = *(const bf16x8*)(p2 + 0);
        h1A = *(const bf16x8*)(p2 + 512);
        l0A = *(const bf16x8*)(p2 + 1024);
        l1A = *(const bf16x8*)(p2 + 1536);
        eA = eeb[(kbase + kt + 2) * 16 + li];
    }

    // ---- shortlist: candidates within EPS of each row's split-local min ----
    EMIT(uA1, uA2, n_base + wv * 32);
    EMIT(uB1, uB2, n_base + wv * 32 + 16);
}

// ---- pass 3: exact f32 recheck + gather + write + loss; 4 THREADS PER POSITION ----
// Lane-quarter q owns v2-indices q+4t (t=0..7). Each lane's partial dot equals the
// original chain's accumulator a_q; the 2-step shfl_xor v2 reduce reproduces
// (a0+a1)+(a2+a3) BITWISE (IEEE add commutative) -> identical argmin/tie-break.
__global__ __launch_bounds__(256) void vq_pick(
        const float* __restrict__ in, const float* __restrict__ emb,
        const float* __restrict__ ee, const unsigned short* __restrict__ cand,
        const unsigned short* __restrict__ cnt, float* __restrict__ out,
        float* __restrict__ partials) {
    const int tid = blockIdx.x * 256 + threadIdx.x;  // 0..524287
    const int n = tid >> 2;                          // position
    const int q = tid & 3;                           // dim quarter (v2-interleaved)
    const int w = n & 63;
    const int h = (n >> 6) & 63;
    const int b = n >> 12;
    const size_t base = ((size_t)b << 18) + ((size_t)h << 6) + (size_t)w;

    // this lane's 8 v2 chunks: v2-index p = q + 4t -> dims 2p, 2p+1
    v2 x[8];
    #pragma unroll
    for (int tt = 0; tt < 8; ++tt) {
        const int p = q + 4 * tt;
        x[tt].x = in[base + ((size_t)(2 * p) << 12)];
        x[tt].y = in[base + ((size_t)(2 * p + 1) << 12)];
    }
    asm volatile("" : "+v"(x[0]), "+v"(x[1]), "+v"(x[2]), "+v"(x[3]),
                      "+v"(x[4]), "+v"(x[5]), "+v"(x[6]), "+v"(x[7]));

    const int c0 = cnt[n];          // split 0: slots 0..5
    const int c1 = cnt[NPOS + n];   // split 1: slots 6..11
    float bestD = 3.4e38f;
    int bestK = 0x7FFFFFFF;
    for (int s = 0; s < c0 + c1; ++s) {
        const int slot = (s < c0) ? s : (MAXC_S + s - c0);
        const int k = (int)cand[n * 12 + slot];
        const v2* __restrict__ e = (const v2*)(emb + (size_t)k * DIM);
        v2 a = {0.f, 0.f};  // == a_q of the original 4-accumulator chain
        #pragma unroll
        for (int tt = 0; tt < 8; ++tt) a = FMA2(x[tt], e[q + 4 * tt], a);
        // (a0+a1)+(a2+a3), componentwise, bitwise-identical on all 4 lanes
        v2 o;
        o.x = __shfl_xor(a.x, 1, 64); o.y = __shfl_xor(a.y, 1, 64);
        a += o;
        o.x = __shfl_xor(a.x, 2, 64); o.y = __shfl_xor(a.y, 2, 64);
        a += o;
        float dk = fmaf(-2.f, a.x + a.y, ee[k]);
        // lexicographic (dist, k) min == ascending-k strict-< first occurrence
        if (dk < bestD || (dk == bestD && k < bestK)) { bestD = dk; bestK = k; }
    }
    if (q == 0) out[OUT_Q + 1 + n] = (float)bestK;

    const v2* __restrict__ eq = (const v2*)(emb + (size_t)bestK * DIM);
    v2 errs2 = {0.f, 0.f};
    #pragma unroll
    for (int tt = 0; tt < 8; ++tt) {
        const int p = q + 4 * tt;
        v2 qv = eq[p];
        v2 diff = qv - x[tt];
        errs2 = FMA2(diff, diff, errs2);
        out[base + ((size_t)(2 * p) << 12)] = qv.x;
        out[base + ((size_t)(2 * p + 1) << 12)] = qv.y;
    }
    float errs = errs2.x + errs2.y;

    #pragma unroll
    for (int off = 32; off > 0; off >>= 1) errs += __shfl_xor(errs, off, 64);

    __shared__ float red[4];
    const int wave = threadIdx.x >> 6;
    const int lane = threadIdx.x & 63;
    if (lane == 0) red[wave] = errs;
    __syncthreads();
    if (threadIdx.x == 0) {
        partials[blockIdx.x] = (red[0] + red[1]) + (red[2] + red[3]);
    }
}

// ---- pass 4: parallel deterministic loss reduction over 2048 partials ----
__global__ __launch_bounds__(256) void vq_loss(const float* __restrict__ partials,
                                               float* __restrict__ out) {
    const int t = threadIdx.x;
    float s = 0.f;
    #pragma unroll
    for (int j = 0; j < 8; ++j) s += partials[t + 256 * j];  // fixed ascending order
    #pragma unroll
    for (int off = 32; off > 0; off >>= 1) s += __shfl_xor(s, off, 64);
    __shared__ float red[4];
    const int wave = t >> 6;
    const int lane = t & 63;
    if (lane == 0) red[wave] = s;
    __syncthreads();
    if (t == 0) {
        out[OUT_Q] = ((red[0] + red[1]) + (red[2] + red[3])) * (float)(1.25 / 8388608.0);
    }
}

extern "C" void kernel_launch(void* const* d_in, const int* in_sizes, int n_in,
                              void* d_out, int out_size, void* d_ws, size_t ws_size,
                              hipStream_t stream) {
    const float* in  = (const float*)d_in[0];   // [32,64,64,64] f32
    const float* emb = (const float*)d_in[1];   // [1024,64] f32
    float* out = (float*)d_out;

    // ws layout: ee f32[1024] | eeb f32[1024+64 pad] | Bpack u16[68*2048 pad] |
    //            cand u16[NPOS*12] | cnt u16[2*NPOS] | partials f32[2048]  (~3.94 MB)
    char* w = (char*)d_ws;
    float* ee = (float*)w;                      w += K_CODES * 4;
    float* eeb = (float*)w;                     w += (K_CODES + 64) * 4;
    unsigned short* Bpack = (unsigned short*)w; w += (size_t)68 * 2048 * 2;
    unsigned short* cand = (unsigned short*)w;  w += (size_t)NPOS * 12 * 2;
    unsigned short* cnt = (unsigned short*)w;   w += (size_t)2 * NPOS * 2;
    float* partials = (float*)w;

    vq_prep<<<256, 256, 0, stream>>>(emb, ee, eeb, Bpack);
    vq_dist_mfma<<<2048, 256, 0, stream>>>(in, Bpack, eeb, cand, cnt);
    vq_pick<<<2048, 256, 0, stream>>>(in, emb, ee, cand, cnt, out, partials);
    vq_loss<<<1, 256, 0, stream>>>(partials, out);
}

// Round 19
// 71.435 us; speedup vs baseline: 1.4656x; 1.1482x over previous
//
#include <hip/hip_runtime.h>

#define K_CODES 1024
#define DIM 64
#define OUT_Q 8388608  // 32*64*64*64 quantized elems; loss at [OUT_Q]; indices at [OUT_Q+1..]
#define NPOS 131072
#define MAXC_S 6       // shortlist slots per split (2 splits share a 12-wide row)
#define EPS 0.05f      // shortlist margin (covers 8-sigma of the x.(2el) 1-word-B error)
#define BIAS 32.0f     // makes packed distances positive (|2*dot| <= ~26 < 32)

typedef float v2 __attribute__((ext_vector_type(2)));
typedef float f32x4 __attribute__((ext_vector_type(4)));
typedef short bf16x8 __attribute__((ext_vector_type(8)));

#if __has_builtin(__builtin_elementwise_fma)
#define FMA2(a, b, c) __builtin_elementwise_fma((a), (b), (c))
#else
static __device__ inline v2 FMA2(v2 a, v2 b, v2 c) {
    v2 r; r.x = fmaf(a.x, b.x, c.x); r.y = fmaf(a.y, b.y, c.y); return r;
}
#endif

static __device__ inline unsigned short f2bf(float f) {  // RNE f32->bf16
    union { float f; unsigned u; } c; c.f = f;
    unsigned u = c.u;
    u += 0x7fffu + ((u >> 16) & 1u);
    return (unsigned short)(u >> 16);
}
static __device__ inline float bf2f(unsigned short h) {
    union { unsigned u; float f; } c; c.u = ((unsigned)h) << 16;
    return c.f;
}

// ---- pass 1: ee[k], biased eeb[k], prepacked B fragments of bf16(-2*e) ----
// SINGLE-WORD B: Bpack[kt][half][lane][j] = bf16(-2*e). 1024 u16 = 2KB per tile.
// B-frag layout for mfma_16x16x32: lane l supplies B[kdim=(l>>4)*8+j][col=l&15].
// PARALLEL: one wave per code k (lane = dim d); 256 blocks x 4 waves.
__global__ __launch_bounds__(256) void vq_prep(
        const float* __restrict__ emb, float* __restrict__ ee,
        float* __restrict__ eeb, unsigned short* __restrict__ Bpack) {
    const int t = threadIdx.x;
    const int wv = t >> 6;
    const int d = t & 63;
    const int k = blockIdx.x * 4 + wv;
    const int kt = k >> 4, col = k & 15;

    const float vv = emb[k * DIM + d];
    float s = vv * vv;
    #pragma unroll
    for (int off = 32; off > 0; off >>= 1) s += __shfl_xor(s, off, 64);
    if (d == 0) {
        ee[k] = s;          // exact-path norm (recheck)
        eeb[k] = s + BIAS;  // biased accumulator seed (approx path)
    }

    const int half = d >> 5;
    const int lane = ((d >> 3) & 3) * 16 + col;
    const int j = d & 7;
    Bpack[kt * 1024 + half * 512 + lane * 8 + j] = f2bf(-2.f * vv);
}

// one A-set vs one tile-PAIR: two ee-seeded 4-MFMA chains (x exact via xh+xl,
// B single bf16 word), merged 3-op/elem packed best-2.
#define PTILE2(XH0, XL0, XH1, XL1, Eh0, Eh1, Oh0, Oh1,                           \
               SE, SO, IDXE, IDXO, U1, U2)                                       \
    {                                                                            \
        f32x4 aE = {SE, SE, SE, SE};                                             \
        aE = __builtin_amdgcn_mfma_f32_16x16x32_bf16(XH0, Eh0, aE, 0, 0, 0);     \
        aE = __builtin_amdgcn_mfma_f32_16x16x32_bf16(XL0, Eh0, aE, 0, 0, 0);     \
        aE = __builtin_amdgcn_mfma_f32_16x16x32_bf16(XH1, Eh1, aE, 0, 0, 0);     \
        aE = __builtin_amdgcn_mfma_f32_16x16x32_bf16(XL1, Eh1, aE, 0, 0, 0);     \
        f32x4 aO = {SO, SO, SO, SO};                                             \
        aO = __builtin_amdgcn_mfma_f32_16x16x32_bf16(XH0, Oh0, aO, 0, 0, 0);     \
        aO = __builtin_amdgcn_mfma_f32_16x16x32_bf16(XL0, Oh0, aO, 0, 0, 0);     \
        aO = __builtin_amdgcn_mfma_f32_16x16x32_bf16(XH1, Oh1, aO, 0, 0, 0);     \
        aO = __builtin_amdgcn_mfma_f32_16x16x32_bf16(XL1, Oh1, aO, 0, 0, 0);     \
        _Pragma("unroll")                                                        \
        for (int j = 0; j < 4; ++j) {                                            \
            unsigned uE = (__float_as_uint(aE[j]) & 0xFFFFFFE0u) | (IDXE);       \
            unsigned uO = (__float_as_uint(aO[j]) & 0xFFFFFFE0u) | (IDXO);       \
            unsigned uu = uE < uO ? uE : uO;                /* v_min_u32 */      \
            unsigned mn = uu < U2[j] ? uu : U2[j];          /* v_min_u32 */      \
            U2[j] = U1[j] > mn ? U1[j] : mn;                /* v_max_u32 */      \
            U1[j] = uu < U1[j] ? uu : U1[j];                /* v_min_u32 */      \
        }                                                                        \
    }

// load one position-tile's A fragments (hi/lo split, 2 K-halves) and pin them
#define LOADA(XH0, XL0, XH1, XL1, POSOFF)                                       \
    {                                                                           \
        _Pragma("unroll")                                                       \
        for (int j = 0; j < 8; ++j) {                                           \
            float v0 = in[ibase + ((size_t)(dbase + j) << 12) + (POSOFF)];      \
            float v1 = in[ibase + ((size_t)(32 + dbase + j) << 12) + (POSOFF)]; \
            unsigned short h0 = f2bf(v0), h1 = f2bf(v1);                        \
            XH0[j] = (short)h0; XL0[j] = (short)f2bf(v0 - bf2f(h0));            \
            XH1[j] = (short)h1; XL1[j] = (short)f2bf(v1 - bf2f(h1));            \
        }                                                                       \
        asm volatile("" : "+v"(XH0), "+v"(XL0), "+v"(XH1), "+v"(XL1));          \
    }

// shortlist emit for one position-tile's merged (U1,U2) candidate sets.
// k = split*512 + f*16 + li where f = packed&31.
#define EMIT(U1a, U2a, PBASE)                                                                        \
    {                                                                                                \
        _Pragma("unroll")                                                                            \
        for (int j = 0; j < 4; ++j) {                                                                \
            unsigned um = U1a[j];                                                                    \
            _Pragma("unroll")                                                                        \
            for (int m = 1; m < 16; m <<= 1) {                                                       \
                unsigned o = (unsigned)__shfl_xor((int)um, m, 64);                                   \
                um = um < o ? um : o;                                                                \
            }                                                                                        \
            const float thr = __uint_as_float(um & 0xFFFFFFE0u) + EPS;                               \
            bool f1 = __uint_as_float(U1a[j] & 0xFFFFFFE0u) <= thr;                                  \
            bool f2 = __uint_as_float(U2a[j] & 0xFFFFFFE0u) <= thr;                                  \
            unsigned long long b1 = __ballot(f1);                                                    \
            unsigned long long b2 = __ballot(f2);                                                    \
            unsigned fl1 = (unsigned)((b1 >> (g * 16)) & 0xFFFFull);                                 \
            unsigned fl2 = (unsigned)((b2 >> (g * 16)) & 0xFFFFull);                                 \
            const unsigned below = (1u << li) - 1u;                                                  \
            int c1 = __popc(fl1);                                                                    \
            int p1 = __popc(fl1 & below);                                                            \
            int p2 = c1 + __popc(fl2 & below);                                                       \
            const int n_row = (PBASE) + g * 4 + j;                                                   \
            unsigned fA = U1a[j] & 31u, fB = U2a[j] & 31u;                                           \
            if (f1 && p1 < MAXC_S)                                                                   \
                cand[n_row * 12 + sb + p1] = (unsigned short)(ksb + fA * 16u + li);                  \
            if (f2 && p2 < MAXC_S)                                                                   \
                cand[n_row * 12 + sb + p2] = (unsigned short)(ksb + fB * 16u + li);                  \
            if (li == 0) {                                                                           \
                int tot = c1 + __popc(fl2);                                                          \
                cnt[cntb + n_row] = (unsigned short)(tot < MAXC_S ? tot : MAXC_S);                   \
            }                                                                                        \
        }                                                                                            \
    }

// ---- pass 2: MFMA approx distances; 32 pos/wave x 512 codes (K-split x2) ----
// R15 streaming structure, 4-MFMA tiles (single-word B): 2 loads/tile, 2KB/tile.
__global__ __launch_bounds__(256, 4) void vq_dist_mfma(
        const float* __restrict__ in, const unsigned short* __restrict__ Bpack,
        const float* __restrict__ eeb,
        unsigned short* __restrict__ cand, unsigned short* __restrict__ cnt) {
    const int t = threadIdx.x;
    const int wv = t >> 6;
    const int l = t & 63;
    const int li = l & 15;
    const int g = l >> 4;
    const int split = blockIdx.x >> 10;       // 0 or 1: code range [split*512, +512)
    const int pblk = blockIdx.x & 1023;
    const int n_base = pblk * 128;            // 128 positions per block (never crosses b)
    const size_t ibase = ((size_t)(n_base >> 12) << 18) + (size_t)(n_base & 4095);
    const int sb = split * MAXC_S;            // slot base within 12-wide cand row
    const unsigned ksb = (unsigned)(split * 512);
    const int cntb = split * NPOS;

    // ---- A fragments: 2 position-tiles x 64 dims, hi/lo split, 2 K-halves ----
    const int dbase = g * 8;
    const int posA = wv * 32 + li;
    bf16x8 XAH0, XAL0, XAH1, XAL1, XBH0, XBL0, XBH1, XBL1;
    LOADA(XAH0, XAL0, XAH1, XAL1, posA);
    LOADA(XBH0, XBL0, XBH1, XBL1, posA + 16);

    unsigned uA1[4], uA2[4], uB1[4], uB2[4];
    #pragma unroll
    for (int j = 0; j < 4; ++j) {
        uA1[j] = uA2[j] = uB1[j] = uB2[j] = 0xFFFFFFFFu;
    }

    // coalesced per-lane stream base within this split's 32-tile range
    const int kbase = split * 32;  // tile units
    const unsigned short* bp = Bpack + (size_t)kbase * 1024 + (size_t)l * 8;

    // preload first tile-pair's even tile into reg set A
    bf16x8 h0A = *(const bf16x8*)(bp + 0);
    bf16x8 h1A = *(const bf16x8*)(bp + 512);
    float eA = eeb[kbase * 16 + li];

    for (int kt = 0; kt < 32; kt += 2) {
        const unsigned idxE = (unsigned)(kt);
        const unsigned idxO = (unsigned)(kt + 1);
        // load odd tile into reg set B
        const unsigned short* p1 = bp + (size_t)(kt + 1) * 1024;
        bf16x8 h0B = *(const bf16x8*)(p1 + 0);
        bf16x8 h1B = *(const bf16x8*)(p1 + 512);
        float eB = eeb[(kbase + kt + 1) * 16 + li];

        PTILE2(XAH0, XAL0, XAH1, XAL1, h0A, h1A, h0B, h1B,
               eA, eB, idxE, idxO, uA1, uA2);
        PTILE2(XBH0, XBL0, XBH1, XBL1, h0A, h1A, h0B, h1B,
               eA, eB, idxE, idxO, uB1, uB2);

        // prefetch next even tile into reg set A (Bpack/eeb padded: safe at end)
        const unsigned short* p2 = bp + (size_t)(kt + 2) * 1024;
        h0A = *(const bf16x8*)(p2 + 0);
        h1A = *(const bf16x8*)(p2 + 512);
        eA = eeb[(kbase + kt + 2) * 16 + li];
    }

    // ---- shortlist: candidates within EPS of each row's split-local min ----
    EMIT(uA1, uA2, n_base + wv * 32);
    EMIT(uB1, uB2, n_base + wv * 32 + 16);
}

// ---- pass 3: exact f32 recheck + gather + write + loss; 4 threads/position ----
// Lane-quarter q owns v2-indices q+4t; shfl_xor v2 reduce reproduces the
// (a0+a1)+(a2+a3) chain BITWISE -> identical argmin/tie-break to the R3 scan.
__global__ __launch_bounds__(256) void vq_pick(
        const float* __restrict__ in, const float* __restrict__ emb,
        const float* __restrict__ ee, const unsigned short* __restrict__ cand,
        const unsigned short* __restrict__ cnt, float* __restrict__ out,
        float* __restrict__ partials) {
    const int tid = blockIdx.x * 256 + threadIdx.x;  // 0..524287
    const int n = tid >> 2;                          // position
    const int q = tid & 3;                           // dim quarter (v2-interleaved)
    const int w = n & 63;
    const int h = (n >> 6) & 63;
    const int b = n >> 12;
    const size_t base = ((size_t)b << 18) + ((size_t)h << 6) + (size_t)w;

    v2 x[8];
    #pragma unroll
    for (int tt = 0; tt < 8; ++tt) {
        const int p = q + 4 * tt;
        x[tt].x = in[base + ((size_t)(2 * p) << 12)];
        x[tt].y = in[base + ((size_t)(2 * p + 1) << 12)];
    }
    asm volatile("" : "+v"(x[0]), "+v"(x[1]), "+v"(x[2]), "+v"(x[3]),
                      "+v"(x[4]), "+v"(x[5]), "+v"(x[6]), "+v"(x[7]));

    const int c0 = cnt[n];          // split 0: slots 0..5
    const int c1 = cnt[NPOS + n];   // split 1: slots 6..11
    float bestD = 3.4e38f;
    int bestK = 0x7FFFFFFF;
    for (int s = 0; s < c0 + c1; ++s) {
        const int slot = (s < c0) ? s : (MAXC_S + s - c0);
        const int k = (int)cand[n * 12 + slot];
        const v2* __restrict__ e = (const v2*)(emb + (size_t)k * DIM);
        v2 a = {0.f, 0.f};
        #pragma unroll
        for (int tt = 0; tt < 8; ++tt) a = FMA2(x[tt], e[q + 4 * tt], a);
        v2 o;
        o.x = __shfl_xor(a.x, 1, 64); o.y = __shfl_xor(a.y, 1, 64);
        a += o;
        o.x = __shfl_xor(a.x, 2, 64); o.y = __shfl_xor(a.y, 2, 64);
        a += o;
        float dk = fmaf(-2.f, a.x + a.y, ee[k]);
        if (dk < bestD || (dk == bestD && k < bestK)) { bestD = dk; bestK = k; }
    }
    if (q == 0) out[OUT_Q + 1 + n] = (float)bestK;

    const v2* __restrict__ eq = (const v2*)(emb + (size_t)bestK * DIM);
    v2 errs2 = {0.f, 0.f};
    #pragma unroll
    for (int tt = 0; tt < 8; ++tt) {
        const int p = q + 4 * tt;
        v2 qv = eq[p];
        v2 diff = qv - x[tt];
        errs2 = FMA2(diff, diff, errs2);
        out[base + ((size_t)(2 * p) << 12)] = qv.x;
        out[base + ((size_t)(2 * p + 1) << 12)] = qv.y;
    }
    float errs = errs2.x + errs2.y;

    #pragma unroll
    for (int off = 32; off > 0; off >>= 1) errs += __shfl_xor(errs, off, 64);

    __shared__ float red[4];
    const int wave = threadIdx.x >> 6;
    const int lane = threadIdx.x & 63;
    if (lane == 0) red[wave] = errs;
    __syncthreads();
    if (threadIdx.x == 0) {
        partials[blockIdx.x] = (red[0] + red[1]) + (red[2] + red[3]);
    }
}

// ---- pass 4: parallel deterministic loss reduction over 2048 partials ----
__global__ __launch_bounds__(256) void vq_loss(const float* __restrict__ partials,
                                               float* __restrict__ out) {
    const int t = threadIdx.x;
    float s = 0.f;
    #pragma unroll
    for (int j = 0; j < 8; ++j) s += partials[t + 256 * j];  // fixed ascending order
    #pragma unroll
    for (int off = 32; off > 0; off >>= 1) s += __shfl_xor(s, off, 64);
    __shared__ float red[4];
    const int wave = t >> 6;
    const int lane = t & 63;
    if (lane == 0) red[wave] = s;
    __syncthreads();
    if (t == 0) {
        out[OUT_Q] = ((red[0] + red[1]) + (red[2] + red[3])) * (float)(1.25 / 8388608.0);
    }
}

extern "C" void kernel_launch(void* const* d_in, const int* in_sizes, int n_in,
                              void* d_out, int out_size, void* d_ws, size_t ws_size,
                              hipStream_t stream) {
    const float* in  = (const float*)d_in[0];   // [32,64,64,64] f32
    const float* emb = (const float*)d_in[1];   // [1024,64] f32
    float* out = (float*)d_out;

    // ws layout: ee f32[1024] | eeb f32[1024+64 pad] | Bpack u16[68*1024 pad] |
    //            cand u16[NPOS*12] | cnt u16[2*NPOS] | partials f32[2048]  (~3.8 MB)
    char* w = (char*)d_ws;
    float* ee = (float*)w;                      w += K_CODES * 4;
    float* eeb = (float*)w;                     w += (K_CODES + 64) * 4;
    unsigned short* Bpack = (unsigned short*)w; w += (size_t)68 * 1024 * 2;
    unsigned short* cand = (unsigned short*)w;  w += (size_t)NPOS * 12 * 2;
    unsigned short* cnt = (unsigned short*)w;   w += (size_t)2 * NPOS * 2;
    float* partials = (float*)w;

    vq_prep<<<256, 256, 0, stream>>>(emb, ee, eeb, Bpack);
    vq_dist_mfma<<<2048, 256, 0, stream>>>(in, Bpack, eeb, cand, cnt);
    vq_pick<<<2048, 256, 0, stream>>>(in, emb, ee, cand, cnt, out, partials);
    vq_loss<<<1, 256, 0, stream>>>(partials, out);
}